// Round 5
// baseline (544.720 us; speedup 1.0000x reference)
//
#include <hip/hip_runtime.h>
#include <hip/hip_bf16.h>

// Problem constants (from the reference)
#define NNZ_TOT   1048576
#define N_IN_SZ   (721 * 1440)   // 1,038,240
#define N_ROWS    (361 * 720)    //   259,920 output cells
#define BC        64             // B*C = 4*16
#define NBKT      ((N_ROWS + 63) / 64)   // 4062 row-buckets of 64 rows
#define BUCKET_CAP 384           // lambda=258, +7.8 sigma; overflow path below
#define OF_CAP    4096

// ---------------- bucket scatter (replaces hist+scan+CSR) ----------------
// entry = { col | (row&63)<<20 , weight_bits } ; col < 2^20, rlo 6 bits.

__global__ void scatter_b_kernel(const int* __restrict__ rows, const int* __restrict__ cols,
                                 const float* __restrict__ S,
                                 int* __restrict__ cursor, int2* __restrict__ epad,
                                 int* __restrict__ of_count, int4* __restrict__ of_list,
                                 int nnz) {
    int k = blockIdx.x * blockDim.x + threadIdx.x;
    if (k >= nnz) return;
    const int r = rows[k];
    const int c = cols[k];
    const float w = S[k];
    const int bkt = r >> 6;
    const int slot = atomicAdd(&cursor[bkt], 1);
    if (slot < BUCKET_CAP) {
        epad[(size_t)bkt * BUCKET_CAP + slot] =
            make_int2(c | ((r & 63) << 20), __float_as_int(w));
    } else {
        int o = atomicAdd(of_count, 1);
        if (o < OF_CAP) of_list[o] = make_int4(r, c, __float_as_int(w), 0);
    }
}

// ---------------- x transpose: [64][N_IN] f32 -> [N_IN][64] bf16 ----------------

__global__ void transpose_kernel(const float* __restrict__ x, __hip_bfloat16* __restrict__ xt) {
    __shared__ float tile[64][65];
    const int c0 = blockIdx.x * 64;
    const int tx = threadIdx.x & 63;
    const int ty = threadIdx.x >> 6;   // 0..3
    const int cr = c0 + tx;
    #pragma unroll
    for (int r = 0; r < 64; r += 4) {
        const int bc = r + ty;
        tile[tx][bc] = (cr < N_IN_SZ) ? x[(size_t)bc * N_IN_SZ + cr] : 0.f;
    }
    __syncthreads();
    #pragma unroll
    for (int r = 0; r < 64; r += 4) {
        const int cy = r + ty;
        const int c = c0 + cy;
        if (c < N_IN_SZ) xt[(size_t)c * 64 + tx] = __float2bfloat16(tile[cy][tx]);
    }
}

// ---------------- gather: block = 64-row bucket x 64 bc, entry-parallel ----------------
// All 4 waves chew the bucket's entry list in interleaved batches of 8 (MLP=8);
// lane = bc; accumulate via LDS float atomics into tile[bc][rlo] (2-way bank alias, free);
// coalesced float4 writeout.

__global__ void gather_b_kernel(const __hip_bfloat16* __restrict__ xt,
                                const int* __restrict__ cursor,
                                const int2* __restrict__ epad,
                                float* __restrict__ y) {
    __shared__ float tile[64][65];
    const int b = blockIdx.x;
    const int lane = threadIdx.x & 63;
    const int wave = threadIdx.x >> 6;
    const int base = b * 64;

    for (int i = threadIdx.x; i < 64 * 65; i += 256) ((float*)tile)[i] = 0.f;
    __syncthreads();

    int cnt = cursor[b];
    if (cnt > BUCKET_CAP) cnt = BUCKET_CAP;
    const int2* __restrict__ eb = epad + (size_t)b * BUCKET_CAP;

    for (int t = wave * 8; t < cnt; t += 32) {
        int n = cnt - t; if (n > 8) n = 8;
        int2 E[8];
        #pragma unroll
        for (int j = 0; j < 8; ++j) if (j < n) E[j] = eb[t + j];      // uniform broadcast
        float xv[8];
        #pragma unroll
        for (int j = 0; j < 8; ++j) if (j < n)
            xv[j] = __bfloat162float(xt[(size_t)(E[j].x & 0xFFFFF) * 64 + lane]);
        #pragma unroll
        for (int j = 0; j < 8; ++j) if (j < n)
            atomicAdd(&tile[lane][E[j].x >> 20], __int_as_float(E[j].y) * xv[j]);
    }
    __syncthreads();

    // writeout: 1024 float4 tasks = 64 bc x 16 quads; 4 per thread
    #pragma unroll
    for (int j = 0; j < 4; ++j) {
        const int task = j * 256 + threadIdx.x;
        const int bc = task >> 4;
        const int r0 = (task & 15) * 4;
        const int i0 = base + r0;
        float4 v = make_float4(tile[bc][r0], tile[bc][r0 + 1],
                               tile[bc][r0 + 2], tile[bc][r0 + 3]);
        float* yp = y + (size_t)bc * N_ROWS;
        if (i0 + 3 < N_ROWS) {
            *(float4*)&yp[i0] = v;
        } else {
            if (i0 + 0 < N_ROWS) yp[i0 + 0] = v.x;
            if (i0 + 1 < N_ROWS) yp[i0 + 1] = v.y;
            if (i0 + 2 < N_ROWS) yp[i0 + 2] = v.z;
            if (i0 + 3 < N_ROWS) yp[i0 + 3] = v.w;
        }
    }
}

// ---------------- overflow cleanup (expected: 0 entries) ----------------

__global__ void cleanup_kernel(const int* __restrict__ of_count,
                               const int4* __restrict__ of_list,
                               const float* __restrict__ x, float* __restrict__ y) {
    int n = *of_count;
    if (n > OF_CAP) n = OF_CAP;
    const int total = n * 64;
    for (int t = blockIdx.x * blockDim.x + threadIdx.x; t < total;
         t += gridDim.x * blockDim.x) {
        const int e = t >> 6, bc = t & 63;
        const int4 E = of_list[e];
        atomicAdd(&y[(size_t)bc * N_ROWS + E.x],
                  __int_as_float(E.z) * x[(size_t)bc * N_IN_SZ + E.y]);
    }
}

// ---------------- last-resort atomic COO ----------------

__global__ void regrid_coo_kernel(const float* __restrict__ x, const float* __restrict__ S,
                                  const int* __restrict__ rows, const int* __restrict__ cols,
                                  float* __restrict__ y, int nnz) {
    const int bc = blockIdx.y;
    const float* __restrict__ xp = x + (size_t)bc * N_IN_SZ;
    float* __restrict__ yp = y + (size_t)bc * N_ROWS;
    int k = blockIdx.x * blockDim.x + threadIdx.x;
    const int stride = gridDim.x * blockDim.x;
    for (; k < nnz; k += stride) {
        atomicAdd(&yp[rows[k]], S[k] * xp[cols[k]]);
    }
}

extern "C" void kernel_launch(void* const* d_in, const int* in_sizes, int n_in,
                              void* d_out, int out_size, void* d_ws, size_t ws_size,
                              hipStream_t stream) {
    const float* x    = (const float*)d_in[0];
    const float* S    = (const float*)d_in[1];
    const int*   rows = (const int*)d_in[2];
    const int*   cols = (const int*)d_in[3];
    float*       y    = (float*)d_out;
    const int nnz = in_sizes[1];

    // Workspace layout (256B-aligned chunks)
    const size_t SZ_CURSOR = ((size_t)NBKT * 4 + 255) & ~255ULL;       // 16.3 KB
    const size_t SZ_OFCNT  = 256;
    const size_t SZ_OFLIST = ((size_t)OF_CAP * 16 + 255) & ~255ULL;    // 64 KB
    const size_t SZ_EPAD   = ((size_t)NBKT * BUCKET_CAP * 8 + 255) & ~255ULL;  // 12.5 MB
    const size_t SZ_XT     = ((size_t)N_IN_SZ * BC * 2 + 255) & ~255ULL;       // 133 MB
    const size_t NEED = SZ_CURSOR + SZ_OFCNT + SZ_OFLIST + SZ_EPAD + SZ_XT;

    if (ws_size < NEED) {
        hipMemsetAsync(d_out, 0, (size_t)out_size * sizeof(float), stream);
        dim3 grid(1024, BC, 1);
        regrid_coo_kernel<<<grid, 256, 0, stream>>>(x, S, rows, cols, y, nnz);
        return;
    }

    char* w = (char*)d_ws;
    int*  cursor   = (int*)(w);
    int*  of_count = (int*)(w + SZ_CURSOR);
    int4* of_list  = (int4*)(w + SZ_CURSOR + SZ_OFCNT);
    int2* epad     = (int2*)(w + SZ_CURSOR + SZ_OFCNT + SZ_OFLIST);
    __hip_bfloat16* xt = (__hip_bfloat16*)(w + SZ_CURSOR + SZ_OFCNT + SZ_OFLIST + SZ_EPAD);

    // zero cursors + overflow count in one memset (contiguous)
    hipMemsetAsync(cursor, 0, SZ_CURSOR + SZ_OFCNT, stream);

    const int tBlocks = (N_IN_SZ + 63) / 64;  // 16,223
    transpose_kernel<<<tBlocks, 256, 0, stream>>>(x, xt);

    const int nnzBlocks = (nnz + 255) / 256;
    scatter_b_kernel<<<nnzBlocks, 256, 0, stream>>>(rows, cols, S, cursor, epad,
                                                    of_count, of_list, nnz);

    gather_b_kernel<<<NBKT, 256, 0, stream>>>(xt, cursor, epad, y);

    cleanup_kernel<<<16, 256, 0, stream>>>(of_count, of_list, x, y);
}